// Round 2
// baseline (16485.185 us; speedup 1.0000x reference)
//
#include <hip/hip_runtime.h>
#include <hip/hip_bf16.h>
#include <math.h>

#define NU 20000
#define NI 20000
#define L  50

// ---------------------------------------------------------------------------
__device__ __forceinline__ float fsig(float x) {
    return __builtin_amdgcn_rcpf(1.f + __expf(-x));
}
__device__ __forceinline__ float ftanh(float x) {
    float t = fminf(2.f * x, 80.f);
    float e2 = __expf(t);
    return (e2 - 1.f) * __builtin_amdgcn_rcpf(e2 + 1.f);
}
__device__ __forceinline__ void loadrow64(float* w, const float* src) {
    const float4* p = (const float4*)src;
    #pragma unroll
    for (int k = 0; k < 16; ++k) {
        float4 v = p[k];
        w[4*k] = v.x; w[4*k+1] = v.y; w[4*k+2] = v.z; w[4*k+3] = v.w;
    }
}
// dot(w[64], x[64]) with 4 accumulators (x = float4* into LDS, broadcast reads)
__device__ __forceinline__ float dot64(const float* w, const float4* x) {
    float a0 = 0.f, a1 = 0.f, a2 = 0.f, a3 = 0.f;
    #pragma unroll
    for (int k = 0; k < 4; ++k) {
        float4 x0 = x[4*k+0], x1 = x[4*k+1], x2 = x[4*k+2], x3 = x[4*k+3];
        const float* wk = w + 16*k;
        a0 += wk[0]*x0.x  + wk[1]*x0.y  + wk[2]*x0.z  + wk[3]*x0.w;
        a1 += wk[4]*x1.x  + wk[5]*x1.y  + wk[6]*x1.z  + wk[7]*x1.w;
        a2 += wk[8]*x2.x  + wk[9]*x2.y  + wk[10]*x2.z + wk[11]*x2.w;
        a3 += wk[12]*x3.x + wk[13]*x3.y + wk[14]*x3.z + wk[15]*x3.w;
    }
    return (a0 + a1) + (a2 + a3);
}

// ---------------------------------------------------------------------------
// K1: Y[r][d] = sum_k X[r][k] * W[d][k]
// ---------------------------------------------------------------------------
__global__ __launch_bounds__(256) void hid_kernel(const float* __restrict__ X,
                                                  const float* __restrict__ W,
                                                  float* __restrict__ Y, int N)
{
    __shared__ float sW[64][65];
    int tid = threadIdx.x;
    for (int i = tid; i < 64 * 64; i += 256) sW[i >> 6][i & 63] = W[i];
    __syncthreads();
    int r = blockIdx.x * 4 + (tid >> 6);
    int d = tid & 63;
    if (r >= N) return;
    const float* x = X + (size_t)r * 64;
    float acc = 0.f;
    #pragma unroll
    for (int k = 0; k < 64; ++k) acc += x[k] * sW[d][k];
    Y[(size_t)r * 64 + d] = acc;
}

// ---------------------------------------------------------------------------
// K3: out[r][d] = tanh( U[d][:64].A[r] + U[d][64:].F[r] )
// ---------------------------------------------------------------------------
__global__ __launch_bounds__(256) void upd_kernel(const float* __restrict__ A,
                                                  const float* __restrict__ F,
                                                  const float* __restrict__ U,
                                                  float* __restrict__ out, int N)
{
    __shared__ float sU[64][130];
    int tid = threadIdx.x;
    for (int i = tid; i < 64 * 128; i += 256) sU[i >> 7][i & 127] = U[i];
    __syncthreads();
    int r = blockIdx.x * 4 + (tid >> 6);
    int d = tid & 63;
    if (r >= N) return;
    const float* a = A + (size_t)r * 64;
    const float* f = F + (size_t)r * 64;
    float acc = 0.f;
    #pragma unroll
    for (int k = 0; k < 64; ++k) acc += a[k] * sU[d][k];
    #pragma unroll
    for (int k = 0; k < 64; ++k) acc += f[k] * sU[d][64 + k];
    out[(size_t)r * 64 + d] = tanhf(acc);
}

// ---------------------------------------------------------------------------
// K2: mailbox reduce, one node per 384-thread block.
//   threads 0..191  : forward GRU rows (gate = g>>6 : 0=r, 1=z, 2=n)
//   threads 192..383: backward GRU rows
// xw precomputed for all steps (use-order) into bf16 LDS; consumed slots are
// recycled as f32 storage for the per-step hidden outputs (gf / gb).
// ---------------------------------------------------------------------------
__global__ __launch_bounds__(384, 3) void reduce_kernel(
    const float* __restrict__ src_hid,   // [Nsrc][64]
    const float* __restrict__ dst_hid,   // [N][64]
    const int*   __restrict__ nbr_idx,   // [N][L]
    const int*   __restrict__ nbr_time,  // [N][L]
    const float* __restrict__ te,        // [L][64]
    const float* __restrict__ te_k,      // [L][64]
    const float* __restrict__ Wi,        // [2][192][64]
    const float* __restrict__ Wh,        // [2][192][64]
    const float* __restrict__ bi,        // [2][192]
    const float* __restrict__ bh,        // [2][192]
    const float* __restrict__ glin,      // [64][128]
    const float* __restrict__ agg,       // [64][128]
    float* __restrict__ out)             // [N][64]
{
    __shared__ float sG[L][64];                              // gin -> g_out
    __shared__ __align__(16) __hip_bfloat16 sXW[2][L][192];  // xw -> gf/gb (f32)
    __shared__ float sR[2][64], sZ[2][64], sH[2][64];
    __shared__ int   s_tm[L], s_nid[L], s_ord[L], s_are[L];
    __shared__ float s_ev[L], s_hid[64];
    __shared__ int   s_lasti;

    const int tid  = threadIdx.x;
    const int n    = blockIdx.x;
    const int lane = tid & 63;
    const int grp  = tid >> 6;           // 0..5
    const int dir  = (tid >= 192) ? 1 : 0;
    const int g    = tid - dir * 192;    // 0..191
    const int gate = g >> 6;             // 0=r 1=z 2=n
    const int d    = g & 63;

    // ---- P0: times/ids, stable rank, argmax(first) ----
    if (tid < L) { s_tm[tid] = nbr_time[(size_t)n*L + tid];
                   s_nid[tid] = nbr_idx[(size_t)n*L + tid]; }
    __syncthreads();
    if (tid < L) {
        int tl = s_tm[tid], rank = 0;
        for (int m = 0; m < L; ++m) {
            int tm = s_tm[m];
            rank += (tm < tl) || (tm == tl && m < tid);
        }
        s_ord[rank] = tid;          // sorted pos -> original slot
        s_are[tid]  = L - 1 - rank; // reversed rank of original slot
    }
    if (tid == 0) {
        int best = 0, bt = s_tm[0];
        for (int m = 1; m < L; ++m) if (s_tm[m] > bt) { bt = s_tm[m]; best = m; }
        s_lasti = best;
    }
    __syncthreads();

    // ---- P1: gather time-sorted mail ----
    for (int t = grp; t < L; t += 6)
        sG[t][lane] = src_hid[(size_t)s_nid[s_ord[t]] * 64 + lane];
    __syncthreads();

    // ---- P2: xw[s] = Wi[g].gin[t(s)] + bi  (use-order, bf16) ----
    {
        float wi[64];
        loadrow64(wi, Wi + (size_t)(dir*192 + g) * 64);
        float bi_v = bi[dir*192 + g];
        for (int s = 0; s < L; ++s) {
            int tt = dir ? (L-1-s) : s;
            float v = dot64(wi, (const float4*)sG[tt]) + bi_v;
            sXW[dir][s][g] = __float2bfloat16(v);
        }
    }

    // ---- P3: both GRU directions concurrently ----
    float wh[64];
    loadrow64(wh, Wh + (size_t)(dir*192 + g) * 64);
    float bh_v = bh[dir*192 + g];
    float hreg = 0.f;
    if (gate == 2) sH[dir][d] = 0.f;
    __syncthreads();

    __hip_bfloat16* xws = &sXW[dir][0][0];
    for (int s = 0; s < L; ++s) {
        float gh  = dot64(wh, (const float4*)sH[dir]) + bh_v;
        float xwv = __bfloat162float(xws[s*192 + g]);
        if (gate == 0)      sR[dir][d] = fsig(xwv + gh);
        else if (gate == 1) sZ[dir][d] = fsig(xwv + gh);
        __syncthreads();
        if (gate == 2) {
            float r  = sR[dir][d];
            float z  = sZ[dir][d];
            float nn = ftanh(xwv + r * gh);
            hreg = (1.f - z) * nn + z * hreg;
            sH[dir][d] = hreg;
            ((float*)(xws + s*192))[d] = hreg;   // gf[t=s] / gb[t=L-1-s]
        }
        __syncthreads();
    }

    // ---- P6: g_out[t][d] = glin[d][:64].gf[t] + glin[d][64:].gb[t] ----
    {
        float ga[64], gb[64];
        loadrow64(ga, glin + (size_t)lane * 128);
        loadrow64(gb, glin + (size_t)lane * 128 + 64);
        for (int t = grp; t < L; t += 6) {
            const float4* fp = (const float4*)(const void*)&sXW[0][t][0];
            const float4* bp = (const float4*)(const void*)&sXW[1][L-1-t][0];
            sG[t][lane] = dot64(ga, fp) + dot64(gb, bp);
        }
    }
    __syncthreads();

    // ---- P7: attention scores + softmax ----
    {
        float dh = dst_hid[(size_t)n * 64 + lane];
        for (int l = grp; l < L; l += 6) {
            float v = (te[(size_t)s_are[l] * 64 + lane] + sG[l][lane]) * dh;
            #pragma unroll
            for (int o = 32; o > 0; o >>= 1) v += __shfl_down(v, o, 64);
            if (lane == 0) s_ev[l] = v * 0.125f;
        }
    }
    __syncthreads();
    if (tid < 64) {
        float v = (tid < L) ? s_ev[tid] : -1e30f;
        float m = v;
        #pragma unroll
        for (int o = 32; o > 0; o >>= 1) m = fmaxf(m, __shfl_xor(m, o, 64));
        float ex = (tid < L) ? __expf(v - m) : 0.f;
        float sm = ex;
        #pragma unroll
        for (int o = 32; o > 0; o >>= 1) sm += __shfl_xor(sm, o, 64);
        if (tid < L) s_ev[tid] = ex * __builtin_amdgcn_rcpf(sm);
    }
    __syncthreads();

    // ---- P8: hid[d] = sum_l alpha[l] * (g_out[l][d] + te_k[are[l]][d]) ----
    if (tid < 64) {
        float acc = 0.f;
        for (int l = 0; l < L; ++l)
            acc += s_ev[l] * (sG[l][tid] + te_k[(size_t)s_are[l] * 64 + tid]);
        s_hid[tid] = acc;
    }
    __syncthreads();

    // ---- P9: out[d] = agg[d][:64].hid + agg[d][64:].last_em ----
    if (tid < 64) {
        const float4* ap = (const float4*)(agg + (size_t)tid * 128);
        const float4* hp = (const float4*)s_hid;
        const float4* lp = (const float4*)(src_hid + (size_t)s_nid[s_lasti] * 64);
        float acc = 0.f;
        #pragma unroll
        for (int k = 0; k < 16; ++k) {
            float4 a = ap[k], h = hp[k];
            acc += a.x*h.x + a.y*h.y + a.z*h.z + a.w*h.w;
        }
        #pragma unroll
        for (int k = 0; k < 16; ++k) {
            float4 a = ap[16 + k], e = lp[k];
            acc += a.x*e.x + a.y*e.y + a.z*e.z + a.w*e.w;
        }
        out[(size_t)n * 64 + tid] = acc;
    }
}

// ---------------------------------------------------------------------------
extern "C" void kernel_launch(void* const* d_in, const int* in_sizes, int n_in,
                              void* d_out, int out_size, void* d_ws, size_t ws_size,
                              hipStream_t stream)
{
    const float* user_feat     = (const float*)d_in[0];
    const float* item_feat     = (const float*)d_in[1];
    const int*   item_nbr_idx  = (const int*)d_in[2];
    const int*   item_nbr_time = (const int*)d_in[3];
    const int*   user_nbr_idx  = (const int*)d_in[4];
    const int*   user_nbr_time = (const int*)d_in[5];
    const float* W_user        = (const float*)d_in[6];
    const float* W_item        = (const float*)d_in[7];
    const float* u_te          = (const float*)d_in[8];
    const float* u_te_k        = (const float*)d_in[9];
    const float* i_te          = (const float*)d_in[10];
    const float* i_te_k        = (const float*)d_in[11];
    const float* gru_u_Wi      = (const float*)d_in[12];
    const float* gru_u_Wh      = (const float*)d_in[13];
    const float* gru_u_bi      = (const float*)d_in[14];
    const float* gru_u_bh      = (const float*)d_in[15];
    const float* gru_i_Wi      = (const float*)d_in[16];
    const float* gru_i_Wh      = (const float*)d_in[17];
    const float* gru_i_bi      = (const float*)d_in[18];
    const float* gru_i_bh      = (const float*)d_in[19];
    const float* gru_lin_u     = (const float*)d_in[20];
    const float* gru_lin_i     = (const float*)d_in[21];
    const float* agg_u         = (const float*)d_in[22];
    const float* agg_i         = (const float*)d_in[23];
    const float* upd_u         = (const float*)d_in[24];
    const float* upd_i         = (const float*)d_in[25];

    float* ws       = (float*)d_ws;
    float* user_hid = ws;
    float* item_hid = user_hid + NU * 64;
    float* item_agg = item_hid + NI * 64;
    float* user_agg = item_agg + NI * 64;

    hid_kernel<<<NU / 4, 256, 0, stream>>>(user_feat, W_user, user_hid, NU);
    hid_kernel<<<NI / 4, 256, 0, stream>>>(item_feat, W_item, item_hid, NI);

    // 'by': user -> item, per item node
    reduce_kernel<<<NI, 384, 0, stream>>>(user_hid, item_hid,
        item_nbr_idx, item_nbr_time, i_te, i_te_k,
        gru_i_Wi, gru_i_Wh, gru_i_bi, gru_i_bh, gru_lin_i, agg_i, item_agg);

    // 'pby': item -> user, per user node
    reduce_kernel<<<NU, 384, 0, stream>>>(item_hid, user_hid,
        user_nbr_idx, user_nbr_time, u_te, u_te_k,
        gru_u_Wi, gru_u_Wh, gru_u_bi, gru_u_bh, gru_lin_u, agg_u, user_agg);

    float* out = (float*)d_out;
    upd_kernel<<<NU / 4, 256, 0, stream>>>(user_agg, user_feat, upd_u, out, NU);
    upd_kernel<<<NI / 4, 256, 0, stream>>>(item_agg, item_feat, upd_i, out + NU * 64, NI);
}

// Round 3
// 15592.323 us; speedup vs baseline: 1.0573x; 1.0573x over previous
//
#include <hip/hip_runtime.h>
#include <math.h>

#define NU 20000
#define NI 20000
#define L  50

// ---------------------------------------------------------------------------
// bf16 helpers (bits in unsigned short / packed pairs in unsigned int)
// ---------------------------------------------------------------------------
__device__ __forceinline__ float bflo(unsigned int u) { return __uint_as_float(u << 16); }
__device__ __forceinline__ float bfhi(unsigned int u) { return __uint_as_float(u & 0xffff0000u); }
__device__ __forceinline__ unsigned short f2bf(float f) {
    unsigned int u = __float_as_uint(f);
    u = u + 0x7fffu + ((u >> 16) & 1u);      // RNE
    return (unsigned short)(u >> 16);
}
__device__ __forceinline__ float bf2f(unsigned short s) {
    return __uint_as_float(((unsigned int)s) << 16);
}
__device__ __forceinline__ float fsig(float x) {
    return __builtin_amdgcn_rcpf(1.f + __expf(-x));
}
__device__ __forceinline__ float ftanh(float x) {
    float t = fminf(2.f * x, 80.f);
    float e2 = __expf(t);
    return (e2 - 1.f) * __builtin_amdgcn_rcpf(e2 + 1.f);
}
__device__ __forceinline__ void loadrow64(float* w, const float* src) {
    const float4* p = (const float4*)src;
    #pragma unroll
    for (int k = 0; k < 16; ++k) {
        float4 v = p[k];
        w[4*k] = v.x; w[4*k+1] = v.y; w[4*k+2] = v.z; w[4*k+3] = v.w;
    }
}
// two dots against the same bf16 x-vector (64 elems packed in 8 uint4)
__device__ __forceinline__ void dot64x2_bf(const float* wA, const float* wB,
                                           const uint4* __restrict__ x,
                                           float& rA, float& rB)
{
    float a0 = 0.f, a1 = 0.f, b0 = 0.f, b1 = 0.f;
    #pragma unroll
    for (int k = 0; k < 8; ++k) {
        uint4 v = x[k];
        float x0 = bflo(v.x), x1 = bfhi(v.x), x2 = bflo(v.y), x3 = bfhi(v.y);
        float x4 = bflo(v.z), x5 = bfhi(v.z), x6 = bflo(v.w), x7 = bfhi(v.w);
        const float* a = wA + 8*k;
        const float* b = wB + 8*k;
        a0 += a[0]*x0 + a[1]*x1 + a[2]*x2 + a[3]*x3;
        a1 += a[4]*x4 + a[5]*x5 + a[6]*x6 + a[7]*x7;
        b0 += b[0]*x0 + b[1]*x1 + b[2]*x2 + b[3]*x3;
        b1 += b[4]*x4 + b[5]*x5 + b[6]*x6 + b[7]*x7;
    }
    rA = a0 + a1; rB = b0 + b1;
}
__device__ __forceinline__ float dot64_bf(const float* w, const uint4* __restrict__ x)
{
    float a0 = 0.f, a1 = 0.f;
    #pragma unroll
    for (int k = 0; k < 8; ++k) {
        uint4 v = x[k];
        const float* a = w + 8*k;
        a0 += a[0]*bflo(v.x) + a[1]*bfhi(v.x) + a[2]*bflo(v.y) + a[3]*bfhi(v.y);
        a1 += a[4]*bflo(v.z) + a[5]*bfhi(v.z) + a[6]*bflo(v.w) + a[7]*bfhi(v.w);
    }
    return a0 + a1;
}

// ---------------------------------------------------------------------------
// K1: Y[r][d] = sum_k X[r][k] * W[d][k]
// ---------------------------------------------------------------------------
__global__ __launch_bounds__(256) void hid_kernel(const float* __restrict__ X,
                                                  const float* __restrict__ W,
                                                  float* __restrict__ Y, int N)
{
    __shared__ float sW[64][65];
    int tid = threadIdx.x;
    for (int i = tid; i < 64 * 64; i += 256) sW[i >> 6][i & 63] = W[i];
    __syncthreads();
    int r = blockIdx.x * 4 + (tid >> 6);
    int d = tid & 63;
    if (r >= N) return;
    const float* x = X + (size_t)r * 64;
    float acc = 0.f;
    #pragma unroll
    for (int k = 0; k < 64; ++k) acc += x[k] * sW[d][k];
    Y[(size_t)r * 64 + d] = acc;
}

// ---------------------------------------------------------------------------
// K3: out[r][d] = tanh( U[d][:64].A[r] + U[d][64:].F[r] )
// ---------------------------------------------------------------------------
__global__ __launch_bounds__(256) void upd_kernel(const float* __restrict__ A,
                                                  const float* __restrict__ F,
                                                  const float* __restrict__ U,
                                                  float* __restrict__ out, int N)
{
    __shared__ float sU[64][130];
    int tid = threadIdx.x;
    for (int i = tid; i < 64 * 128; i += 256) sU[i >> 7][i & 127] = U[i];
    __syncthreads();
    int r = blockIdx.x * 4 + (tid >> 6);
    int d = tid & 63;
    if (r >= N) return;
    const float* a = A + (size_t)r * 64;
    const float* f = F + (size_t)r * 64;
    float acc = 0.f;
    #pragma unroll
    for (int k = 0; k < 64; ++k) acc += a[k] * sU[d][k];
    #pragma unroll
    for (int k = 0; k < 64; ++k) acc += f[k] * sU[d][64 + k];
    out[(size_t)r * 64 + d] = tanhf(acc);
}

// ---------------------------------------------------------------------------
// K2: mailbox reduce, one node per 192-thread block (3 waves).
// Thread t owns TWO gate-rows of ONE direction:
//   dir = t >= 96,  g0 = t - dir*96,  g1 = g0 + 96   (rows 0..191 covered)
// so one broadcast h-read feeds 128 FMAs. Weights live in ONE reused
// register pair w0[64]/w1[64] (Wi -> Wh -> glin). h state is bf16 in LDS.
// ---------------------------------------------------------------------------
__global__ __launch_bounds__(192, 2) void reduce_kernel(
    const float* __restrict__ src_hid,   // [Nsrc][64]
    const float* __restrict__ dst_hid,   // [N][64]
    const int*   __restrict__ nbr_idx,   // [N][L]
    const int*   __restrict__ nbr_time,  // [N][L]
    const float* __restrict__ te,        // [L][64]
    const float* __restrict__ te_k,      // [L][64]
    const float* __restrict__ Wi,        // [2][192][64]
    const float* __restrict__ Wh,        // [2][192][64]
    const float* __restrict__ bi,        // [2][192]
    const float* __restrict__ bh,        // [2][192]
    const float* __restrict__ glin,      // [64][128]
    const float* __restrict__ agg,       // [64][128]
    float* __restrict__ out)             // [N][64]
{
    __shared__ __align__(16) unsigned short sXW[2][L][192]; // xw bf16; slot [s][0:64) recycled to h-history
    __shared__ __align__(16) unsigned short sGmail[L][64];  // sorted mail, bf16
    __shared__ float sGout[L][64];
    __shared__ float sGH[2][192];
    __shared__ __align__(16) unsigned short sH[2][64];
    __shared__ int   s_tm[L], s_nid[L], s_ord[L], s_are[L];
    __shared__ float s_ev[L], s_hid[64];
    __shared__ int   s_lasti;

    const int tid  = threadIdx.x;          // 0..191
    const int n    = blockIdx.x;
    const int lane = tid & 63;
    const int wv   = tid >> 6;             // 0..2
    const int dir  = (tid >= 96) ? 1 : 0;
    const int g0   = tid - dir * 96;       // 0..95
    const int g1   = g0 + 96;              // 96..191

    float w0[64], w1[64];

    // ---- P0: times/ids, stable rank, argmax(first) ----
    if (tid < L) { s_tm[tid] = nbr_time[(size_t)n*L + tid];
                   s_nid[tid] = nbr_idx[(size_t)n*L + tid]; }
    __syncthreads();
    if (tid < L) {
        int tl = s_tm[tid], rank = 0;
        for (int m = 0; m < L; ++m) {
            int tm = s_tm[m];
            rank += (tm < tl) || (tm == tl && m < tid);
        }
        s_ord[rank] = tid;          // sorted pos -> original slot
        s_are[tid]  = L - 1 - rank; // reversed rank of original slot
    }
    if (tid == 0) {
        int best = 0, bt = s_tm[0];
        for (int m = 1; m < L; ++m) if (s_tm[m] > bt) { bt = s_tm[m]; best = m; }
        s_lasti = best;
    }
    __syncthreads();

    // ---- P1: gather time-sorted mail (bf16) ----
    for (int t = wv; t < L; t += 3)
        sGmail[t][lane] = f2bf(src_hid[(size_t)s_nid[s_ord[t]] * 64 + lane]);
    __syncthreads();

    // ---- P2: xw[dir][s][g] = Wi[g].gin[t(s)] + bi ----
    loadrow64(w0, Wi + (size_t)(dir*192 + g0) * 64);
    loadrow64(w1, Wi + (size_t)(dir*192 + g1) * 64);
    {
        float bi0 = bi[dir*192 + g0];
        float bi1 = bi[dir*192 + g1];
        for (int s = 0; s < L; ++s) {
            int tt = dir ? (L-1-s) : s;
            float xa, xb;
            dot64x2_bf(w0, w1, (const uint4*)sGmail[tt], xa, xb);
            sXW[dir][s][g0] = f2bf(xa + bi0);
            sXW[dir][s][g1] = f2bf(xb + bi1);
        }
    }

    // ---- P3: both GRU directions, 2 rows/thread ----
    loadrow64(w0, Wh + (size_t)(dir*192 + g0) * 64);
    loadrow64(w1, Wh + (size_t)(dir*192 + g1) * 64);
    float bh0 = bh[dir*192 + g0];
    float bh1 = bh[dir*192 + g1];
    float hreg = 0.f;
    if (tid < 128) { sH[tid >> 6][tid & 63] = 0; }
    __syncthreads();

    for (int s = 0; s < L; ++s) {
        // phase A: gh for both rows
        float ga, gb;
        dot64x2_bf(w0, w1, (const uint4*)sH[dir], ga, gb);
        sGH[dir][g0] = ga + bh0;
        sGH[dir][g1] = gb + bh1;
        __syncthreads();
        // phase B: gate combine (threads 0..127 = dir2*64 + d)
        if (tid < 128) {
            int dir2 = tid >> 6, d = tid & 63;
            float ghr = sGH[dir2][d];
            float ghz = sGH[dir2][64 + d];
            float ghn = sGH[dir2][128 + d];
            float xwr = bf2f(sXW[dir2][s][d]);
            float xwz = bf2f(sXW[dir2][s][64 + d]);
            float xwn = bf2f(sXW[dir2][s][128 + d]);
            float r  = fsig(xwr + ghr);
            float z  = fsig(xwz + ghz);
            float nn = ftanh(xwn + r * ghn);
            hreg = (1.f - z) * nn + z * hreg;
            unsigned short hb = f2bf(hreg);
            sH[dir2][d]      = hb;   // next-step state
            sXW[dir2][s][d]  = hb;   // history: gf[t=s] / gb[t=L-1-s]
        }
        __syncthreads();
    }

    // ---- P6: g_out[t][d] = glin[d][:64].gf[t] + glin[d][64:].gb[t] ----
    {
        int d = lane;
        loadrow64(w0, glin + (size_t)d * 128);
        loadrow64(w1, glin + (size_t)d * 128 + 64);
        for (int t = wv; t < L; t += 3) {
            const uint4* fp = (const uint4*)&sXW[0][t][0];
            const uint4* bp = (const uint4*)&sXW[1][L-1-t][0];
            sGout[t][d] = dot64_bf(w0, fp) + dot64_bf(w1, bp);
        }
    }
    __syncthreads();

    // ---- P7: attention scores + softmax ----
    {
        float dh = dst_hid[(size_t)n * 64 + lane];
        for (int l = wv; l < L; l += 3) {
            float v = (te[(size_t)s_are[l] * 64 + lane] + sGout[l][lane]) * dh;
            #pragma unroll
            for (int o = 32; o > 0; o >>= 1) v += __shfl_down(v, o, 64);
            if (lane == 0) s_ev[l] = v * 0.125f;
        }
    }
    __syncthreads();
    if (tid < 64) {
        float v = (tid < L) ? s_ev[tid] : -1e30f;
        float m = v;
        #pragma unroll
        for (int o = 32; o > 0; o >>= 1) m = fmaxf(m, __shfl_xor(m, o, 64));
        float ex = (tid < L) ? __expf(v - m) : 0.f;
        float sm = ex;
        #pragma unroll
        for (int o = 32; o > 0; o >>= 1) sm += __shfl_xor(sm, o, 64);
        if (tid < L) s_ev[tid] = ex * __builtin_amdgcn_rcpf(sm);
    }
    __syncthreads();

    // ---- P8: hid[d] = sum_l alpha[l] * (g_out[l][d] + te_k[are[l]][d]) ----
    if (tid < 64) {
        float acc = 0.f;
        for (int l = 0; l < L; ++l)
            acc += s_ev[l] * (sGout[l][tid] + te_k[(size_t)s_are[l] * 64 + tid]);
        s_hid[tid] = acc;
    }
    __syncthreads();

    // ---- P9: out[d] = agg[d][:64].hid + agg[d][64:].last_em ----
    if (tid < 64) {
        const float4* ap = (const float4*)(agg + (size_t)tid * 128);
        const float4* hp = (const float4*)s_hid;
        const float4* lp = (const float4*)(src_hid + (size_t)s_nid[s_lasti] * 64);
        float acc = 0.f;
        #pragma unroll
        for (int k = 0; k < 16; ++k) {
            float4 a = ap[k], h = hp[k];
            acc += a.x*h.x + a.y*h.y + a.z*h.z + a.w*h.w;
        }
        #pragma unroll
        for (int k = 0; k < 16; ++k) {
            float4 a = ap[16 + k], e = lp[k];
            acc += a.x*e.x + a.y*e.y + a.z*e.z + a.w*e.w;
        }
        out[(size_t)n * 64 + tid] = acc;
    }
}

// ---------------------------------------------------------------------------
extern "C" void kernel_launch(void* const* d_in, const int* in_sizes, int n_in,
                              void* d_out, int out_size, void* d_ws, size_t ws_size,
                              hipStream_t stream)
{
    const float* user_feat     = (const float*)d_in[0];
    const float* item_feat     = (const float*)d_in[1];
    const int*   item_nbr_idx  = (const int*)d_in[2];
    const int*   item_nbr_time = (const int*)d_in[3];
    const int*   user_nbr_idx  = (const int*)d_in[4];
    const int*   user_nbr_time = (const int*)d_in[5];
    const float* W_user        = (const float*)d_in[6];
    const float* W_item        = (const float*)d_in[7];
    const float* u_te          = (const float*)d_in[8];
    const float* u_te_k        = (const float*)d_in[9];
    const float* i_te          = (const float*)d_in[10];
    const float* i_te_k        = (const float*)d_in[11];
    const float* gru_u_Wi      = (const float*)d_in[12];
    const float* gru_u_Wh      = (const float*)d_in[13];
    const float* gru_u_bi      = (const float*)d_in[14];
    const float* gru_u_bh      = (const float*)d_in[15];
    const float* gru_i_Wi      = (const float*)d_in[16];
    const float* gru_i_Wh      = (const float*)d_in[17];
    const float* gru_i_bi      = (const float*)d_in[18];
    const float* gru_i_bh      = (const float*)d_in[19];
    const float* gru_lin_u     = (const float*)d_in[20];
    const float* gru_lin_i     = (const float*)d_in[21];
    const float* agg_u         = (const float*)d_in[22];
    const float* agg_i         = (const float*)d_in[23];
    const float* upd_u         = (const float*)d_in[24];
    const float* upd_i         = (const float*)d_in[25];

    float* ws       = (float*)d_ws;
    float* user_hid = ws;
    float* item_hid = user_hid + NU * 64;
    float* item_agg = item_hid + NI * 64;
    float* user_agg = item_agg + NI * 64;

    hid_kernel<<<NU / 4, 256, 0, stream>>>(user_feat, W_user, user_hid, NU);
    hid_kernel<<<NI / 4, 256, 0, stream>>>(item_feat, W_item, item_hid, NI);

    // 'by': user -> item, per item node
    reduce_kernel<<<NI, 192, 0, stream>>>(user_hid, item_hid,
        item_nbr_idx, item_nbr_time, i_te, i_te_k,
        gru_i_Wi, gru_i_Wh, gru_i_bi, gru_i_bh, gru_lin_i, agg_i, item_agg);

    // 'pby': item -> user, per user node
    reduce_kernel<<<NU, 192, 0, stream>>>(item_hid, user_hid,
        user_nbr_idx, user_nbr_time, u_te, u_te_k,
        gru_u_Wi, gru_u_Wh, gru_u_bi, gru_u_bh, gru_lin_u, agg_u, user_agg);

    float* out = (float*)d_out;
    upd_kernel<<<NU / 4, 256, 0, stream>>>(user_agg, user_feat, upd_u, out, NU);
    upd_kernel<<<NI / 4, 256, 0, stream>>>(item_agg, item_feat, upd_i, out + NU * 64, NI);
}

// Round 4
// 4130.184 us; speedup vs baseline: 3.9914x; 3.7752x over previous
//
#include <hip/hip_runtime.h>
#include <math.h>

#define NU 20000
#define NI 20000
#define L  50

typedef __attribute__((ext_vector_type(8))) short bfx8;
typedef __attribute__((ext_vector_type(4))) float f32x4;

// ---------------------------------------------------------------------------
__device__ __forceinline__ float bflo(unsigned int u) { return __uint_as_float(u << 16); }
__device__ __forceinline__ float bfhi(unsigned int u) { return __uint_as_float(u & 0xffff0000u); }
__device__ __forceinline__ unsigned short f2bf(float f) {
    unsigned int u = __float_as_uint(f);
    u = u + 0x7fffu + ((u >> 16) & 1u);      // RNE
    return (unsigned short)(u >> 16);
}
__device__ __forceinline__ float bf2f(unsigned short s) {
    return __uint_as_float(((unsigned int)s) << 16);
}
__device__ __forceinline__ float fsig(float x) {
    return __builtin_amdgcn_rcpf(1.f + __expf(-x));
}
__device__ __forceinline__ float ftanh(float x) {
    float t = fminf(2.f * x, 80.f);
    float e2 = __expf(t);
    return (e2 - 1.f) * __builtin_amdgcn_rcpf(e2 + 1.f);
}
// 8 consecutive f32 from global -> bf16x8 fragment
__device__ __forceinline__ bfx8 pack_bf8(const float* p) {
    float4 a = ((const float4*)p)[0];
    float4 b = ((const float4*)p)[1];
    bfx8 r;
    r[0]=(short)f2bf(a.x); r[1]=(short)f2bf(a.y); r[2]=(short)f2bf(a.z); r[3]=(short)f2bf(a.w);
    r[4]=(short)f2bf(b.x); r[5]=(short)f2bf(b.y); r[6]=(short)f2bf(b.z); r[7]=(short)f2bf(b.w);
    return r;
}

// ---------------------------------------------------------------------------
// K1: Y[r][d] = sum_k X[r][k] * W[d][k]
// ---------------------------------------------------------------------------
__global__ __launch_bounds__(256) void hid_kernel(const float* __restrict__ X,
                                                  const float* __restrict__ W,
                                                  float* __restrict__ Y, int N)
{
    __shared__ float sW[64][65];
    int tid = threadIdx.x;
    for (int i = tid; i < 64 * 64; i += 256) sW[i >> 6][i & 63] = W[i];
    __syncthreads();
    int r = blockIdx.x * 4 + (tid >> 6);
    int d = tid & 63;
    if (r >= N) return;
    const float* x = X + (size_t)r * 64;
    float acc = 0.f;
    #pragma unroll
    for (int k = 0; k < 64; ++k) acc += x[k] * sW[d][k];
    Y[(size_t)r * 64 + d] = acc;
}

// ---------------------------------------------------------------------------
// K3: out[r][d] = tanh( U[d][:64].A[r] + U[d][64:].F[r] )
// ---------------------------------------------------------------------------
__global__ __launch_bounds__(256) void upd_kernel(const float* __restrict__ A,
                                                  const float* __restrict__ F,
                                                  const float* __restrict__ U,
                                                  float* __restrict__ out, int N)
{
    __shared__ float sU[64][130];
    int tid = threadIdx.x;
    for (int i = tid; i < 64 * 128; i += 256) sU[i >> 7][i & 127] = U[i];
    __syncthreads();
    int r = blockIdx.x * 4 + (tid >> 6);
    int d = tid & 63;
    if (r >= N) return;
    const float* a = A + (size_t)r * 64;
    const float* f = F + (size_t)r * 64;
    float acc = 0.f;
    #pragma unroll
    for (int k = 0; k < 64; ++k) acc += a[k] * sU[d][k];
    #pragma unroll
    for (int k = 0; k < 64; ++k) acc += f[k] * sU[d][64 + k];
    out[(size_t)r * 64 + d] = tanhf(acc);
}

// ---------------------------------------------------------------------------
// K2: mailbox reduce, one node per 256-thread block (4 waves), MFMA-based.
//  P2 xw:    [50x64]@[64x192] per dir, M-tiles over t, N-tiles over gates.
//  P3 GRU:   wave0=fwd, wave1=bwd, A = h replicated over 16 rows, no barriers.
//  P4 glin:  [50x128]@[128x64], one N-tile per wave.
// LDS overlays: sBC = sMail[64][72] (gather..xw) then sHist[64][136]
// (serial..glin); sGout[50][72] overlays dead sXW.
// ---------------------------------------------------------------------------
__global__ __launch_bounds__(256, 2) void reduce_kernel(
    const float* __restrict__ src_hid,   // [Nsrc][64]
    const float* __restrict__ dst_hid,   // [N][64]
    const int*   __restrict__ nbr_idx,   // [N][L]
    const int*   __restrict__ nbr_time,  // [N][L]
    const float* __restrict__ te,        // [L][64]
    const float* __restrict__ te_k,      // [L][64]
    const float* __restrict__ Wi,        // [2][192][64]
    const float* __restrict__ Wh,        // [2][192][64]
    const float* __restrict__ bi,        // [2][192]
    const float* __restrict__ bh,        // [2][192]
    const float* __restrict__ glin,     // [64][128]
    const float* __restrict__ agg,       // [64][128]
    float* __restrict__ out)             // [N][64]
{
    __shared__ __align__(16) unsigned short sXW[2][192][50]; // xw (bf16); later sGout[50][72]
    __shared__ __align__(16) unsigned short sBC[64 * 136];   // sMail[64][72] -> sHist[64][136]
    __shared__ __align__(16) unsigned short sH[2][64];       // current h per dir (bf16)
    __shared__ int   s_tm[L], s_nid[L], s_ord[L], s_are[L];
    __shared__ float s_ev[L], s_hid[64];
    __shared__ int   s_lasti;

    const int tid  = threadIdx.x;
    const int n    = blockIdx.x;
    const int lane = tid & 63;
    const int wv   = tid >> 6;            // 0..3
    const int l15  = lane & 15;
    const int lk8  = (lane >> 4) * 8;

    unsigned short* sGout = &sXW[0][0][0];  // [50][72] bf16, valid after P3

    // ---- P0: times/ids, stable rank, argmax(first) ----
    if (tid < L) { s_tm[tid] = nbr_time[(size_t)n*L + tid];
                   s_nid[tid] = nbr_idx[(size_t)n*L + tid]; }
    __syncthreads();
    if (tid < L) {
        int tl = s_tm[tid], rank = 0;
        for (int m = 0; m < L; ++m) {
            int tm = s_tm[m];
            rank += (tm < tl) || (tm == tl && m < tid);
        }
        s_ord[rank] = tid;          // sorted pos -> original slot
        s_are[tid]  = L - 1 - rank; // reversed rank of original slot
    }
    if (tid == 0) {
        int best = 0, bt = s_tm[0];
        for (int m = 1; m < L; ++m) if (s_tm[m] > bt) { bt = s_tm[m]; best = m; }
        s_lasti = best;
    }
    __syncthreads();

    // ---- P1: gather time-sorted mail -> sMail (bf16, rows 50..63 garbage) ----
    for (int t = wv; t < L; t += 4)
        sBC[t*72 + lane] = f2bf(src_hid[(size_t)s_nid[s_ord[t]] * 64 + lane]);
    __syncthreads();

    // ---- P2: xw = mail @ Wi^T + bi  (MFMA), store bf16 [dir][gate][step] ----
    {
        bfx8 af[4][2];
        #pragma unroll
        for (int mt = 0; mt < 4; ++mt)
            #pragma unroll
            for (int kt = 0; kt < 2; ++kt)
                af[mt][kt] = *(const bfx8*)(&sBC[(mt*16 + l15)*72 + kt*32 + lk8]);
        for (int it = wv; it < 24; it += 4) {
            int dir = it / 12, nt = it - dir*12;
            int g = nt*16 + l15;
            const float* wrow = Wi + (size_t)(dir*192 + g) * 64;
            bfx8 b0 = pack_bf8(wrow + lk8);
            bfx8 b1 = pack_bf8(wrow + 32 + lk8);
            float big = bi[dir*192 + g];
            #pragma unroll
            for (int mt = 0; mt < 4; ++mt) {
                f32x4 acc = {0.f, 0.f, 0.f, 0.f};
                acc = __builtin_amdgcn_mfma_f32_16x16x32_bf16(af[mt][0], b0, acc, 0, 0, 0);
                acc = __builtin_amdgcn_mfma_f32_16x16x32_bf16(af[mt][1], b1, acc, 0, 0, 0);
                #pragma unroll
                for (int r = 0; r < 4; ++r) {
                    int t = mt*16 + (lane >> 4)*4 + r;
                    if (t < L) {
                        int s = dir ? (L-1-t) : t;   // bwd consumes reversed input
                        sXW[dir][g][s] = f2bf(acc[r] + big);
                    }
                }
            }
        }
    }
    __syncthreads();

    // ---- P3: serial GRU, wave0=fwd wave1=bwd, no block barriers inside ----
    if (wv < 2) {
        const int dir = wv;
        bfx8 whf0[12], whf1[12];
        float bhr[12];
        #pragma unroll
        for (int nt = 0; nt < 12; ++nt) {
            const float* wrow = Wh + (size_t)(dir*192 + nt*16 + l15) * 64;
            whf0[nt] = pack_bf8(wrow + lk8);
            whf1[nt] = pack_bf8(wrow + 32 + lk8);
            bhr[nt]  = bh[dir*192 + nt*16 + l15];
        }
        sH[dir][lane] = 0;
        float hp[4] = {0.f, 0.f, 0.f, 0.f};
        const unsigned short* xwb = &sXW[dir][0][0];
        for (int q = 0; q < 25; ++q) {
            unsigned int xp[12];
            #pragma unroll
            for (int nt = 0; nt < 12; ++nt)   // 2 steps' xw per read (aligned u32)
                xp[nt] = *(const unsigned int*)(xwb + (nt*16 + l15)*50 + 2*q);
            #pragma unroll
            for (int r = 0; r < 2; ++r) {
                // A = h replicated over all 16 M-rows (broadcast LDS read)
                bfx8 a0 = *(const bfx8*)(&sH[dir][lk8]);
                bfx8 a1 = *(const bfx8*)(&sH[dir][32 + lk8]);
                f32x4 acc[12];
                #pragma unroll
                for (int nt = 0; nt < 12; ++nt) {
                    f32x4 z = {0.f, 0.f, 0.f, 0.f};
                    z = __builtin_amdgcn_mfma_f32_16x16x32_bf16(a0, whf0[nt], z, 0, 0, 0);
                    z = __builtin_amdgcn_mfma_f32_16x16x32_bf16(a1, whf1[nt], z, 0, 0, 0);
                    acc[nt] = z;
                }
                int s = 2*q + r;
                int t = dir ? (L-1-s) : s;
                unsigned short hb[4];
                #pragma unroll
                for (int c = 0; c < 4; ++c) {       // lane owns d = c*16 + l15
                    float ghr = acc[c][0]     + bhr[c];
                    float ghz = acc[4 + c][0] + bhr[4 + c];
                    float ghn = acc[8 + c][0] + bhr[8 + c];
                    float xwr = r ? bfhi(xp[c])     : bflo(xp[c]);
                    float xwz = r ? bfhi(xp[4 + c]) : bflo(xp[4 + c]);
                    float xwn = r ? bfhi(xp[8 + c]) : bflo(xp[8 + c]);
                    float rr = fsig(xwr + ghr);
                    float zz = fsig(xwz + ghz);
                    float nn = ftanh(xwn + rr * ghn);
                    hp[c] = (1.f - zz) * nn + zz * hp[c];
                    hb[c] = f2bf(hp[c]);
                }
                if ((lane >> 4) == 0) {             // de-duplicate writes
                    #pragma unroll
                    for (int c = 0; c < 4; ++c) {
                        sH[dir][c*16 + l15] = hb[c];
                        sBC[t*136 + dir*64 + c*16 + l15] = hb[c];  // sHist
                    }
                }
            }
        }
    }
    __syncthreads();

    // ---- P4: g_out = hist @ glin^T  (MFMA), wave wv = N-tile wv ----
    {
        bfx8 af[4][4];
        #pragma unroll
        for (int mt = 0; mt < 4; ++mt)
            #pragma unroll
            for (int kt = 0; kt < 4; ++kt)
                af[mt][kt] = *(const bfx8*)(&sBC[(mt*16 + l15)*136 + kt*32 + lk8]);
        bfx8 bfr[4];
        #pragma unroll
        for (int kt = 0; kt < 4; ++kt)
            bfr[kt] = pack_bf8(glin + (size_t)(wv*16 + l15)*128 + kt*32 + lk8);
        #pragma unroll
        for (int mt = 0; mt < 4; ++mt) {
            f32x4 acc = {0.f, 0.f, 0.f, 0.f};
            #pragma unroll
            for (int kt = 0; kt < 4; ++kt)
                acc = __builtin_amdgcn_mfma_f32_16x16x32_bf16(af[mt][kt], bfr[kt], acc, 0, 0, 0);
            #pragma unroll
            for (int r = 0; r < 4; ++r) {
                int t = mt*16 + (lane >> 4)*4 + r;
                if (t < L) sGout[t*72 + wv*16 + l15] = f2bf(acc[r]);
            }
        }
    }
    __syncthreads();

    // ---- P7: attention scores + softmax ----
    {
        float dh = dst_hid[(size_t)n * 64 + lane];
        for (int l2 = wv; l2 < L; l2 += 4) {
            float v = (te[(size_t)s_are[l2]*64 + lane] + bf2f(sGout[l2*72 + lane])) * dh;
            #pragma unroll
            for (int o = 32; o > 0; o >>= 1) v += __shfl_down(v, o, 64);
            if (lane == 0) s_ev[l2] = v * 0.125f;
        }
    }
    __syncthreads();
    if (tid < 64) {
        float v = (tid < L) ? s_ev[tid] : -1e30f;
        float m = v;
        #pragma unroll
        for (int o = 32; o > 0; o >>= 1) m = fmaxf(m, __shfl_xor(m, o, 64));
        float ex = (tid < L) ? __expf(v - m) : 0.f;
        float sm = ex;
        #pragma unroll
        for (int o = 32; o > 0; o >>= 1) sm += __shfl_xor(sm, o, 64);
        if (tid < L) s_ev[tid] = ex * __builtin_amdgcn_rcpf(sm);
    }
    __syncthreads();

    // ---- P8: hid[d] = sum_l alpha[l] * (g_out[l][d] + te_k[are[l]][d]) ----
    if (tid < 64) {
        float acc = 0.f;
        for (int l = 0; l < L; ++l)
            acc += s_ev[l] * (bf2f(sGout[l*72 + tid]) + te_k[(size_t)s_are[l]*64 + tid]);
        s_hid[tid] = acc;
    }
    __syncthreads();

    // ---- P9: out[d] = agg[d][:64].hid + agg[d][64:].last_em ----
    if (tid < 64) {
        const float4* ap = (const float4*)(agg + (size_t)tid * 128);
        const float4* hp4 = (const float4*)s_hid;
        const float4* lp = (const float4*)(src_hid + (size_t)s_nid[s_lasti] * 64);
        float acc = 0.f;
        #pragma unroll
        for (int k = 0; k < 16; ++k) {
            float4 a = ap[k], h = hp4[k];
            acc += a.x*h.x + a.y*h.y + a.z*h.z + a.w*h.w;
        }
        #pragma unroll
        for (int k = 0; k < 16; ++k) {
            float4 a = ap[16 + k], e = lp[k];
            acc += a.x*e.x + a.y*e.y + a.z*e.z + a.w*e.w;
        }
        out[(size_t)n * 64 + tid] = acc;
    }
}

// ---------------------------------------------------------------------------
extern "C" void kernel_launch(void* const* d_in, const int* in_sizes, int n_in,
                              void* d_out, int out_size, void* d_ws, size_t ws_size,
                              hipStream_t stream)
{
    const float* user_feat     = (const float*)d_in[0];
    const float* item_feat     = (const float*)d_in[1];
    const int*   item_nbr_idx  = (const int*)d_in[2];
    const int*   item_nbr_time = (const int*)d_in[3];
    const int*   user_nbr_idx  = (const int*)d_in[4];
    const int*   user_nbr_time = (const int*)d_in[5];
    const float* W_user        = (const float*)d_in[6];
    const float* W_item        = (const float*)d_in[7];
    const float* u_te          = (const float*)d_in[8];
    const float* u_te_k        = (const float*)d_in[9];
    const float* i_te          = (const float*)d_in[10];
    const float* i_te_k        = (const float*)d_in[11];
    const float* gru_u_Wi      = (const float*)d_in[12];
    const float* gru_u_Wh      = (const float*)d_in[13];
    const float* gru_u_bi      = (const float*)d_in[14];
    const float* gru_u_bh      = (const float*)d_in[15];
    const float* gru_i_Wi      = (const float*)d_in[16];
    const float* gru_i_Wh      = (const float*)d_in[17];
    const float* gru_i_bi      = (const float*)d_in[18];
    const float* gru_i_bh      = (const float*)d_in[19];
    const float* gru_lin_u     = (const float*)d_in[20];
    const float* gru_lin_i     = (const float*)d_in[21];
    const float* agg_u         = (const float*)d_in[22];
    const float* agg_i         = (const float*)d_in[23];
    const float* upd_u         = (const float*)d_in[24];
    const float* upd_i         = (const float*)d_in[25];

    float* ws       = (float*)d_ws;
    float* user_hid = ws;
    float* item_hid = user_hid + NU * 64;
    float* item_agg = item_hid + NI * 64;
    float* user_agg = item_agg + NI * 64;

    hid_kernel<<<NU / 4, 256, 0, stream>>>(user_feat, W_user, user_hid, NU);
    hid_kernel<<<NI / 4, 256, 0, stream>>>(item_feat, W_item, item_hid, NI);

    // 'by': user -> item, per item node
    reduce_kernel<<<NI, 256, 0, stream>>>(user_hid, item_hid,
        item_nbr_idx, item_nbr_time, i_te, i_te_k,
        gru_i_Wi, gru_i_Wh, gru_i_bi, gru_i_bh, gru_lin_i, agg_i, item_agg);

    // 'pby': item -> user, per user node
    reduce_kernel<<<NU, 256, 0, stream>>>(item_hid, user_hid,
        user_nbr_idx, user_nbr_time, u_te, u_te_k,
        gru_u_Wi, gru_u_Wh, gru_u_bi, gru_u_bh, gru_lin_u, agg_u, user_agg);

    float* out = (float*)d_out;
    upd_kernel<<<NU / 4, 256, 0, stream>>>(user_agg, user_feat, upd_u, out, NU);
    upd_kernel<<<NI / 4, 256, 0, stream>>>(item_agg, item_feat, upd_i, out + NU * 64, NI);
}

// Round 5
// 2646.410 us; speedup vs baseline: 6.2293x; 1.5607x over previous
//
#include <hip/hip_runtime.h>
#include <math.h>

#define NU 20000
#define NI 20000
#define L  50
#define NODES 16

typedef __attribute__((ext_vector_type(8))) short bfx8;
typedef __attribute__((ext_vector_type(4))) float f32x4;
typedef unsigned short u16;
typedef unsigned char  u8;
typedef unsigned int   u32;

// ---- LDS layout (bytes) ----
#define OFF_MAIL  0        // u16 [16][50][72]           = 115200
#define OFF_XW    115200   // uint2 [2][2][12][16][4]    = 24576  (scratch: sTM/sNID, sGLT)
#define OFF_H     139776   // u16 [2][16][72]            = 4608
#define OFF_EF    144384   // f32 [16][52]               = 3328   (scratch: sDST u16[16][72])
#define OFF_EB    147712   // f32 [16][52]               = 3328   (scratch: sBETA u16[16][72])
#define OFF_AT    151040   // f32 [16][52]  ted -> alpha = 3328
#define OFF_V     154368   // u16 [2][16][72]            = 4608
#define OFF_ORD   158976   // u8  [16][52]               = 832
#define OFF_ARE   159808   // u8  [16][52]               = 832
#define OFF_LASTN 160640   // int [16]                   = 64
#define SMEM_SZ   160704

// ---------------------------------------------------------------------------
__device__ __forceinline__ float bflo(u32 u) { return __uint_as_float(u << 16); }
__device__ __forceinline__ float bfhi(u32 u) { return __uint_as_float(u & 0xffff0000u); }
__device__ __forceinline__ u16 f2bf(float f) {
    u32 u = __float_as_uint(f);
    u = u + 0x7fffu + ((u >> 16) & 1u);      // RNE
    return (u16)(u >> 16);
}
__device__ __forceinline__ float bf2f(u16 s) {
    return __uint_as_float(((u32)s) << 16);
}
__device__ __forceinline__ float fsig(float x) {
    return __builtin_amdgcn_rcpf(1.f + __expf(-x));
}
__device__ __forceinline__ float ftanh(float x) {
    float t = fminf(2.f * x, 80.f);
    float e2 = __expf(t);
    return (e2 - 1.f) * __builtin_amdgcn_rcpf(e2 + 1.f);
}
__device__ __forceinline__ bfx8 pack_bf8(const float* p) {
    float4 a = ((const float4*)p)[0];
    float4 b = ((const float4*)p)[1];
    bfx8 r;
    r[0]=(short)f2bf(a.x); r[1]=(short)f2bf(a.y); r[2]=(short)f2bf(a.z); r[3]=(short)f2bf(a.w);
    r[4]=(short)f2bf(b.x); r[5]=(short)f2bf(b.y); r[6]=(short)f2bf(b.z); r[7]=(short)f2bf(b.w);
    return r;
}
__device__ __forceinline__ float xget(uint2 u, int r) {
    switch (r) {
        case 0: return bflo(u.x);
        case 1: return bfhi(u.x);
        case 2: return bflo(u.y);
        default: return bfhi(u.y);
    }
}

// ---------------------------------------------------------------------------
// K1: Y[r][d] = sum_k X[r][k] * W[d][k]
// ---------------------------------------------------------------------------
__global__ __launch_bounds__(256) void hid_kernel(const float* __restrict__ X,
                                                  const float* __restrict__ W,
                                                  float* __restrict__ Y, int N)
{
    __shared__ float sW[64][65];
    int tid = threadIdx.x;
    for (int i = tid; i < 64 * 64; i += 256) sW[i >> 6][i & 63] = W[i];
    __syncthreads();
    int r = blockIdx.x * 4 + (tid >> 6);
    int d = tid & 63;
    if (r >= N) return;
    const float* x = X + (size_t)r * 64;
    float acc = 0.f;
    #pragma unroll
    for (int k = 0; k < 64; ++k) acc += x[k] * sW[d][k];
    Y[(size_t)r * 64 + d] = acc;
}

// ---------------------------------------------------------------------------
// K3: out[r][d] = tanh( U[d][:64].A[r] + U[d][64:].F[r] )
// ---------------------------------------------------------------------------
__global__ __launch_bounds__(256) void upd_kernel(const float* __restrict__ A,
                                                  const float* __restrict__ F,
                                                  const float* __restrict__ U,
                                                  float* __restrict__ out, int N)
{
    __shared__ float sU[64][130];
    int tid = threadIdx.x;
    for (int i = tid; i < 64 * 128; i += 256) sU[i >> 7][i & 127] = U[i];
    __syncthreads();
    int r = blockIdx.x * 4 + (tid >> 6);
    int d = tid & 63;
    if (r >= N) return;
    const float* a = A + (size_t)r * 64;
    const float* f = F + (size_t)r * 64;
    float acc = 0.f;
    #pragma unroll
    for (int k = 0; k < 64; ++k) acc += a[k] * sU[d][k];
    #pragma unroll
    for (int k = 0; k < 64; ++k) acc += f[k] * sU[d][64 + k];
    out[(size_t)r * 64 + d] = tanhf(acc);
}

// ---------------------------------------------------------------------------
// K2: 16 nodes per 256-thread block.
//  wave0: xw producer (fwd)   wave1: GRU consumer (fwd)
//  wave2: xw producer (bwd)   wave3: GRU consumer (bwd)
// Two serial passes: A) collect attention scores e via v = glin^T.dst ;
// B) accumulate hsum = sum_t alpha[t]*h[t]. Then hid = glin@hsum + beta@te_k,
// out = agg @ [hid || last_em].
// ---------------------------------------------------------------------------
__global__ __launch_bounds__(256, 1) void reduce16(
    const float* __restrict__ src_hid,   // [Nsrc][64]
    const float* __restrict__ dst_hid,   // [N][64]
    const int*   __restrict__ nbr_idx,   // [N][L]
    const int*   __restrict__ nbr_time,  // [N][L]
    const float* __restrict__ te,        // [L][64]
    const float* __restrict__ te_k,      // [L][64]
    const float* __restrict__ Wi,        // [2][192][64]
    const float* __restrict__ Wh,        // [2][192][64]
    const float* __restrict__ bi,        // [2][192]
    const float* __restrict__ bh,        // [2][192]
    const float* __restrict__ glin,      // [64][128]
    const float* __restrict__ agg,       // [64][128]
    float* __restrict__ out)             // [N][64]
{
    extern __shared__ char smem[];
    u16*   sMail  = (u16*)(smem + OFF_MAIL);
    uint2* sXWu   = (uint2*)(smem + OFF_XW);
    u16*   sH     = (u16*)(smem + OFF_H);
    float* sEF    = (float*)(smem + OFF_EF);
    float* sEB    = (float*)(smem + OFF_EB);
    float* sAT    = (float*)(smem + OFF_AT);
    u16*   sV     = (u16*)(smem + OFF_V);
    u8*    sORD   = (u8*)(smem + OFF_ORD);
    u8*    sARE   = (u8*)(smem + OFF_ARE);
    int*   sLASTN = (int*)(smem + OFF_LASTN);

    const int tid  = threadIdx.x;
    const int lane = tid & 63;
    const int wv   = tid >> 6;          // 0..3
    const int l15  = lane & 15;
    const int grp  = lane >> 4;         // 0..3
    const int lk8  = grp * 8;           // bf16 element offset of k-slice
    const int nb   = blockIdx.x * NODES;
    const int dir  = wv >> 1;           // 0=fwd 1=bwd
    const int role = wv & 1;            // 0=producer 1=consumer

    // ---- PH0: load times/ids (scratch in XW region), stable rank, argmax ----
    int* sTM  = (int*)(smem + OFF_XW);
    int* sNID = sTM + NODES * L;
    for (int p = tid; p < NODES * L; p += 256) {
        sTM[p]  = nbr_time[(size_t)nb * L + p];
        sNID[p] = nbr_idx[(size_t)nb * L + p];
    }
    __syncthreads();
    for (int p = tid; p < NODES * L; p += 256) {
        int m = p / L, l = p - m * L;
        int tl = sTM[p], rank = 0;
        for (int mm = 0; mm < L; ++mm) {
            int tm = sTM[m * L + mm];
            rank += (tm < tl) || (tm == tl && mm < l);
        }
        sORD[m * 52 + rank] = (u8)l;
        sARE[m * 52 + l]    = (u8)(L - 1 - rank);
    }
    if (tid < NODES) {
        int best = 0, bt = sTM[tid * L];
        for (int mm = 1; mm < L; ++mm) {
            int tm = sTM[tid * L + mm];
            if (tm > bt) { bt = tm; best = mm; }
        }
        sLASTN[tid] = sNID[tid * L + best];
    }
    __syncthreads();

    // ---- PH1: gather time-sorted mail (bf16) + stage dst ----
    u16* sDST = (u16*)(smem + OFF_EF);
    #pragma unroll 2
    for (int q = wv; q < NODES * L; q += 4) {
        int m = q / L, t = q - m * L;
        int row = sNID[m * L + sORD[m * 52 + t]];
        sMail[(size_t)q * 72 + lane] = f2bf(src_hid[(size_t)row * 64 + lane]);
    }
    for (int p = tid; p < NODES * 64; p += 256) {
        int m = p >> 6, d = p & 63;
        sDST[m * 72 + d] = f2bf(dst_hid[(size_t)(nb + m) * 64 + d]);
    }
    __syncthreads();

    // ---- PH2: glin^T stage (XW scratch), v-GEMMs, ted ----
    u16* sGLT = (u16*)(smem + OFF_XW);   // [128][72]
    for (int p = tid; p < 8192; p += 256) {
        int d = p >> 7, j = p & 127;
        sGLT[j * 72 + d] = f2bf(glin[(size_t)d * 128 + j]);
    }
    __syncthreads();
    if (wv < 2) {
        // v[wv][m][j] = sum_d dst[m][d] * glin[d][wv*64 + j]
        bfx8 a0 = *(const bfx8*)(sDST + l15 * 72 + lk8);
        bfx8 a1 = *(const bfx8*)(sDST + l15 * 72 + 32 + lk8);
        #pragma unroll
        for (int nt = 0; nt < 4; ++nt) {
            bfx8 b0 = *(const bfx8*)(sGLT + (wv * 64 + nt * 16 + l15) * 72 + lk8);
            bfx8 b1 = *(const bfx8*)(sGLT + (wv * 64 + nt * 16 + l15) * 72 + 32 + lk8);
            f32x4 acc = {0.f, 0.f, 0.f, 0.f};
            acc = __builtin_amdgcn_mfma_f32_16x16x32_bf16(a0, b0, acc, 0, 0, 0);
            acc = __builtin_amdgcn_mfma_f32_16x16x32_bf16(a1, b1, acc, 0, 0, 0);
            #pragma unroll
            for (int r = 0; r < 4; ++r)
                sV[(wv * 16 + grp * 4 + r) * 72 + nt * 16 + l15] = f2bf(acc[r]);
        }
    } else {
        // ted[m][l] = te[are[m][l]] . dst[m]
        for (int p = tid - 128; p < NODES * L; p += 128) {
            int m = p / L, l = p - m * L;
            const float* tp = te + (size_t)sARE[m * 52 + l] * 64;
            float acc = 0.f;
            #pragma unroll 8
            for (int k = 0; k < 64; ++k) acc += tp[k] * bf2f(sDST[m * 72 + k]);
            sAT[m * 52 + l] = acc;
        }
    }
    __syncthreads();

    // ---- preload weight fragments (Wi for producers, Wh for consumers) ----
    bfx8 wF[12][2];
    float bv[12];
    {
        const float* Wsrc = role ? Wh : Wi;
        const float* bsrc = role ? bh : bi;
        #pragma unroll
        for (int nt = 0; nt < 12; ++nt) {
            const float* wrow = Wsrc + (size_t)(dir * 192 + nt * 16 + l15) * 64;
            wF[nt][0] = pack_bf8(wrow + lk8);
            wF[nt][1] = pack_bf8(wrow + 32 + lk8);
            bv[nt] = bsrc[dir * 192 + nt * 16 + l15];
        }
    }
    float vv[4][4];
    if (role) {
        #pragma unroll
        for (int c = 0; c < 4; ++c)
            #pragma unroll
            for (int r = 0; r < 4; ++r)
                vv[c][r] = bf2f(sV[(dir * 16 + grp * 4 + r) * 72 + c * 16 + l15]);
    }
    float* sE = dir ? sEB : sEF;
    float hp[4][4], S[4][4];

    auto produce = [&](int step, int buf) {
        int tt = dir ? (L - 1 - step) : step;
        const u16* mrow = sMail + ((size_t)l15 * L + tt) * 72;
        bfx8 a0 = *(const bfx8*)(mrow + lk8);
        bfx8 a1 = *(const bfx8*)(mrow + 32 + lk8);
        #pragma unroll
        for (int nt = 0; nt < 12; ++nt) {
            f32x4 acc = {0.f, 0.f, 0.f, 0.f};
            acc = __builtin_amdgcn_mfma_f32_16x16x32_bf16(a0, wF[nt][0], acc, 0, 0, 0);
            acc = __builtin_amdgcn_mfma_f32_16x16x32_bf16(a1, wF[nt][1], acc, 0, 0, 0);
            uint2 pk;
            pk.x = (u32)f2bf(acc[0] + bv[nt]) | ((u32)f2bf(acc[1] + bv[nt]) << 16);
            pk.y = (u32)f2bf(acc[2] + bv[nt]) | ((u32)f2bf(acc[3] + bv[nt]) << 16);
            sXWu[(((dir * 2 + buf) * 12 + nt) * 16 + l15) * 4 + grp] = pk;
        }
    };

    auto consume = [&](int s, int buf, int pass) {
        uint2 xwu[12];
        #pragma unroll
        for (int nt = 0; nt < 12; ++nt)
            xwu[nt] = sXWu[(((dir * 2 + buf) * 12 + nt) * 16 + l15) * 4 + grp];
        const u16* hrow = sH + (dir * 16 + l15) * 72;
        bfx8 a0 = *(const bfx8*)(hrow + lk8);
        bfx8 a1 = *(const bfx8*)(hrow + 32 + lk8);
        f32x4 accd[12];
        #pragma unroll
        for (int nt = 0; nt < 12; ++nt) {
            f32x4 z = {0.f, 0.f, 0.f, 0.f};
            z = __builtin_amdgcn_mfma_f32_16x16x32_bf16(a0, wF[nt][0], z, 0, 0, 0);
            z = __builtin_amdgcn_mfma_f32_16x16x32_bf16(a1, wF[nt][1], z, 0, 0, 0);
            accd[nt] = z;
        }
        int t = dir ? (L - 1 - s) : s;
        float al[4];
        if (pass == 1) {
            #pragma unroll
            for (int r = 0; r < 4; ++r) al[r] = sAT[(grp * 4 + r) * 52 + t];
        }
        float pe[4] = {0.f, 0.f, 0.f, 0.f};
        #pragma unroll
        for (int c = 0; c < 4; ++c) {
            #pragma unroll
            for (int r = 0; r < 4; ++r) {
                float ghr = accd[c][r]     + bv[c];
                float ghz = accd[4 + c][r] + bv[4 + c];
                float ghn = accd[8 + c][r] + bv[8 + c];
                float xwr = xget(xwu[c], r);
                float xwz = xget(xwu[4 + c], r);
                float xwn = xget(xwu[8 + c], r);
                float rr = fsig(xwr + ghr);
                float zz = fsig(xwz + ghz);
                float nn = ftanh(xwn + rr * ghn);
                float h  = (1.f - zz) * nn + zz * hp[c][r];
                hp[c][r] = h;
                sH[(dir * 16 + grp * 4 + r) * 72 + c * 16 + l15] = f2bf(h);
                if (pass == 0) pe[r] += h * vv[c][r];
                else           S[c][r] += al[r] * h;
            }
        }
        if (pass == 0) {
            #pragma unroll
            for (int r = 0; r < 4; ++r) {
                #pragma unroll
                for (int msk = 1; msk < 16; msk <<= 1)
                    pe[r] += __shfl_xor(pe[r], msk, 64);
            }
            if (l15 == 0) {
                #pragma unroll
                for (int r = 0; r < 4; ++r)
                    sE[(grp * 4 + r) * 52 + t] = pe[r];
            }
        }
    };

    // ---- PH3/PH5: the two serial passes ----
    for (int pass = 0; pass < 2; ++pass) {
        if (role == 0) {
            produce(0, 0);
        } else {
            #pragma unroll
            for (int c = 0; c < 4; ++c)
                #pragma unroll
                for (int r = 0; r < 4; ++r) {
                    hp[c][r] = 0.f; S[c][r] = (pass == 0) ? S[c][r] : 0.f;
                    sH[(dir * 16 + grp * 4 + r) * 72 + c * 16 + l15] = 0;
                }
        }
        __syncthreads();
        for (int s = 0; s < L; ++s) {
            if (role == 0) {
                if (s + 1 < L) produce(s + 1, (s + 1) & 1);
            } else {
                consume(s, s & 1, pass);
            }
            __syncthreads();
        }
        if (pass == 0) {
            // ---- PH4: softmax over t per node; alpha -> sAT ----
            if (tid < NODES) {
                int m = tid;
                float mx = -1e30f;
                for (int t = 0; t < L; ++t) {
                    float v = (sEF[m * 52 + t] + sEB[m * 52 + t] + sAT[m * 52 + t]) * 0.125f;
                    sEF[m * 52 + t] = v;
                    mx = fmaxf(mx, v);
                }
                float sum = 0.f;
                for (int t = 0; t < L; ++t) {
                    float ex = __expf(sEF[m * 52 + t] - mx);
                    sEF[m * 52 + t] = ex;
                    sum += ex;
                }
                float rs = __builtin_amdgcn_rcpf(sum);
                for (int t = 0; t < L; ++t) sAT[m * 52 + t] = sEF[m * 52 + t] * rs;
            }
            __syncthreads();
        }
    }

    // ---- PH6: epilogue (mail region is dead -> sHS / sA9 / sTKT) ----
    u16* sHS   = (u16*)(smem + OFF_MAIL);            // [16][136] bf16  hsum f||b
    u16* sA9   = sHS + 16 * 136;                     // [16][136] bf16  hid || last_em
    u16* sTKT  = sA9 + 16 * 136;                     // [64][72]  bf16  te_k^T (zero-padded)
    u16* sBETA = (u16*)(smem + OFF_EB);              // [16][72]  bf16

    if (role == 1) {
        #pragma unroll
        for (int c = 0; c < 4; ++c)
            #pragma unroll
            for (int r = 0; r < 4; ++r)
                sHS[(grp * 4 + r) * 136 + dir * 64 + c * 16 + l15] = f2bf(S[c][r]);
    }
    if (tid < NODES) {
        for (int t = 0; t < L; ++t)
            sBETA[tid * 72 + sARE[tid * 52 + t]] = f2bf(sAT[tid * 52 + t]);
        for (int j = L; j < 64; ++j) sBETA[tid * 72 + j] = 0;
    }
    for (int p = tid; p < 4096; p += 256) {
        int j = p >> 6, d = p & 63;
        sTKT[d * 72 + j] = (j < L) ? f2bf(te_k[(size_t)j * 64 + d]) : (u16)0;
    }
    for (int p = tid; p < NODES * 64; p += 256) {
        int m = p >> 6, d = p & 63;
        sA9[m * 136 + 64 + d] = f2bf(src_hid[(size_t)sLASTN[m] * 64 + d]);
    }
    __syncthreads();

    // hid[m][d] = glin[d][:].hsum[m] + te_k^T[d][:].beta[m]  (wave wv = N-tile)
    {
        int nt = wv;
        bfx8 aH[4], aB[2];
        #pragma unroll
        for (int kt = 0; kt < 4; ++kt)
            aH[kt] = *(const bfx8*)(sHS + l15 * 136 + kt * 32 + lk8);
        #pragma unroll
        for (int kt = 0; kt < 2; ++kt)
            aB[kt] = *(const bfx8*)(sBETA + l15 * 72 + kt * 32 + lk8);
        f32x4 acc = {0.f, 0.f, 0.f, 0.f};
        #pragma unroll
        for (int kt = 0; kt < 4; ++kt) {
            bfx8 b = pack_bf8(glin + (size_t)(nt * 16 + l15) * 128 + kt * 32 + lk8);
            acc = __builtin_amdgcn_mfma_f32_16x16x32_bf16(aH[kt], b, acc, 0, 0, 0);
        }
        #pragma unroll
        for (int kt = 0; kt < 2; ++kt) {
            bfx8 b = *(const bfx8*)(sTKT + (nt * 16 + l15) * 72 + kt * 32 + lk8);
            acc = __builtin_amdgcn_mfma_f32_16x16x32_bf16(aB[kt], b, acc, 0, 0, 0);
        }
        #pragma unroll
        for (int r = 0; r < 4; ++r)
            sA9[(grp * 4 + r) * 136 + nt * 16 + l15] = f2bf(acc[r]);
    }
    __syncthreads();

    // out[m][d] = agg[d][:64].hid[m] + agg[d][64:].last_em[m]
    {
        int nt = wv;
        bfx8 aA[4];
        #pragma unroll
        for (int kt = 0; kt < 4; ++kt)
            aA[kt] = *(const bfx8*)(sA9 + l15 * 136 + kt * 32 + lk8);
        f32x4 acc = {0.f, 0.f, 0.f, 0.f};
        #pragma unroll
        for (int kt = 0; kt < 4; ++kt) {
            bfx8 b = pack_bf8(agg + (size_t)(nt * 16 + l15) * 128 + kt * 32 + lk8);
            acc = __builtin_amdgcn_mfma_f32_16x16x32_bf16(aA[kt], b, acc, 0, 0, 0);
        }
        #pragma unroll
        for (int r = 0; r < 4; ++r)
            out[(size_t)(nb + grp * 4 + r) * 64 + nt * 16 + l15] = acc[r];
    }
}

// ---------------------------------------------------------------------------
extern "C" void kernel_launch(void* const* d_in, const int* in_sizes, int n_in,
                              void* d_out, int out_size, void* d_ws, size_t ws_size,
                              hipStream_t stream)
{
    const float* user_feat     = (const float*)d_in[0];
    const float* item_feat     = (const float*)d_in[1];
    const int*   item_nbr_idx  = (const int*)d_in[2];
    const int*   item_nbr_time = (const int*)d_in[3];
    const int*   user_nbr_idx  = (const int*)d_in[4];
    const int*   user_nbr_time = (const int*)d_in[5];
    const float* W_user        = (const float*)d_in[6];
    const float* W_item        = (const float*)d_in[7];
    const float* u_te          = (const float*)d_in[8];
    const float* u_te_k        = (const float*)d_in[9];
    const float* i_te          = (const float*)d_in[10];
    const float* i_te_k        = (const float*)d_in[11];
    const float* gru_u_Wi      = (const float*)d_in[12];
    const float* gru_u_Wh      = (const float*)d_in[13];
    const float* gru_u_bi      = (const float*)d_in[14];
    const float* gru_u_bh      = (const float*)d_in[15];
    const float* gru_i_Wi      = (const float*)d_in[16];
    const float* gru_i_Wh      = (const float*)d_in[17];
    const float* gru_i_bi      = (const float*)d_in[18];
    const float* gru_i_bh      = (const float*)d_in[19];
    const float* gru_lin_u     = (const float*)d_in[20];
    const float* gru_lin_i     = (const float*)d_in[21];
    const float* agg_u         = (const float*)d_in[22];
    const float* agg_i         = (const float*)d_in[23];
    const float* upd_u         = (const float*)d_in[24];
    const float* upd_i         = (const float*)d_in[25];

    float* ws       = (float*)d_ws;
    float* user_hid = ws;
    float* item_hid = user_hid + NU * 64;
    float* item_agg = item_hid + NI * 64;
    float* user_agg = item_agg + NI * 64;

    static int smem_set = 0;
    (void)hipFuncSetAttribute((const void*)reduce16,
                              hipFuncAttributeMaxDynamicSharedMemorySize, SMEM_SZ);
    (void)smem_set;

    hid_kernel<<<NU / 4, 256, 0, stream>>>(user_feat, W_user, user_hid, NU);
    hid_kernel<<<NI / 4, 256, 0, stream>>>(item_feat, W_item, item_hid, NI);

    // 'by': user -> item, per item node
    reduce16<<<NI / NODES, 256, SMEM_SZ, stream>>>(user_hid, item_hid,
        item_nbr_idx, item_nbr_time, i_te, i_te_k,
        gru_i_Wi, gru_i_Wh, gru_i_bi, gru_i_bh, gru_lin_i, agg_i, item_agg);

    // 'pby': item -> user, per user node
    reduce16<<<NU / NODES, 256, SMEM_SZ, stream>>>(item_hid, user_hid,
        user_nbr_idx, user_nbr_time, u_te, u_te_k,
        gru_u_Wi, gru_u_Wh, gru_u_bi, gru_u_bh, gru_lin_u, agg_u, user_agg);

    float* out = (float*)d_out;
    upd_kernel<<<NU / 4, 256, 0, stream>>>(user_agg, user_feat, upd_u, out, NU);
    upd_kernel<<<NI / 4, 256, 0, stream>>>(item_agg, item_feat, upd_i, out + NU * 64, NI);
}

// Round 6
// 1590.117 us; speedup vs baseline: 10.3673x; 1.6643x over previous
//
#include <hip/hip_runtime.h>
#include <math.h>

#define NU 20000
#define NI 20000
#define L  50
#define NODES 16

typedef __attribute__((ext_vector_type(8))) short bfx8;
typedef __attribute__((ext_vector_type(4))) float f32x4;
typedef unsigned short u16;
typedef unsigned char  u8;
typedef unsigned int   u32;

// ---- LDS layout (bytes), static 48832 total ----
#define OFF_XW    0        // uint2 [2][2][12][16][4]    = 24576
                           //   scratch PH0: sTM[800] sNID[800] (6400)
                           //   scratch PH2: sGLT u16[128][72] (18432)
                           //   scratch PH6: sHS/sA9 u16[16][136]x2, sTKT u16[64][72] (17920)
#define OFF_H     24576    // u16 [2][16][72]            = 4608
#define OFF_EF    29184    // f32 [16][52]               = 3328   (scratch: sDST u16[16][72])
#define OFF_EB    32512    // f32 [16][52]               = 3328   (scratch: sBETA u16[16][72])
#define OFF_AT    35840    // f32 [16][52]  ted -> alpha = 3328
#define OFF_V     39168    // u16 [2][16][72]            = 4608
#define OFF_ORD   43776    // u8  [16][52]               = 832
#define OFF_ARE   44608    // u8  [16][52]               = 832
#define OFF_RID   45440    // int [16][52] sorted row id = 3328
#define OFF_LASTN 48768    // int [16]                   = 64
#define SMEM_SZ   48832

// ---------------------------------------------------------------------------
__device__ __forceinline__ float bflo(u32 u) { return __uint_as_float(u << 16); }
__device__ __forceinline__ float bfhi(u32 u) { return __uint_as_float(u & 0xffff0000u); }
__device__ __forceinline__ u16 f2bf(float f) {
    u32 u = __float_as_uint(f);
    u = u + 0x7fffu + ((u >> 16) & 1u);      // RNE
    return (u16)(u >> 16);
}
__device__ __forceinline__ float bf2f(u16 s) {
    return __uint_as_float(((u32)s) << 16);
}
__device__ __forceinline__ float fsig(float x) {
    return __builtin_amdgcn_rcpf(1.f + __expf(-x));
}
__device__ __forceinline__ float ftanh(float x) {
    float t = fminf(2.f * x, 80.f);
    float e2 = __expf(t);
    return (e2 - 1.f) * __builtin_amdgcn_rcpf(e2 + 1.f);
}
__device__ __forceinline__ bfx8 pack_bf8(const float* p) {
    float4 a = ((const float4*)p)[0];
    float4 b = ((const float4*)p)[1];
    bfx8 r;
    r[0]=(short)f2bf(a.x); r[1]=(short)f2bf(a.y); r[2]=(short)f2bf(a.z); r[3]=(short)f2bf(a.w);
    r[4]=(short)f2bf(b.x); r[5]=(short)f2bf(b.y); r[6]=(short)f2bf(b.z); r[7]=(short)f2bf(b.w);
    return r;
}
__device__ __forceinline__ float xget(uint2 u, int r) {
    switch (r) {
        case 0: return bflo(u.x);
        case 1: return bfhi(u.x);
        case 2: return bflo(u.y);
        default: return bfhi(u.y);
    }
}

// ---------------------------------------------------------------------------
// K1: Y[r][d] = sum_k X[r][k] * W[d][k]
// ---------------------------------------------------------------------------
__global__ __launch_bounds__(256) void hid_kernel(const float* __restrict__ X,
                                                  const float* __restrict__ W,
                                                  float* __restrict__ Y, int N)
{
    __shared__ float sW[64][65];
    int tid = threadIdx.x;
    for (int i = tid; i < 64 * 64; i += 256) sW[i >> 6][i & 63] = W[i];
    __syncthreads();
    int r = blockIdx.x * 4 + (tid >> 6);
    int d = tid & 63;
    if (r >= N) return;
    const float* x = X + (size_t)r * 64;
    float acc = 0.f;
    #pragma unroll
    for (int k = 0; k < 64; ++k) acc += x[k] * sW[d][k];
    Y[(size_t)r * 64 + d] = acc;
}

// ---------------------------------------------------------------------------
// K3: out[r][d] = tanh( U[d][:64].A[r] + U[d][64:].F[r] )
// ---------------------------------------------------------------------------
__global__ __launch_bounds__(256) void upd_kernel(const float* __restrict__ A,
                                                  const float* __restrict__ F,
                                                  const float* __restrict__ U,
                                                  float* __restrict__ out, int N)
{
    __shared__ float sU[64][130];
    int tid = threadIdx.x;
    for (int i = tid; i < 64 * 128; i += 256) sU[i >> 7][i & 127] = U[i];
    __syncthreads();
    int r = blockIdx.x * 4 + (tid >> 6);
    int d = tid & 63;
    if (r >= N) return;
    const float* a = A + (size_t)r * 64;
    const float* f = F + (size_t)r * 64;
    float acc = 0.f;
    #pragma unroll
    for (int k = 0; k < 64; ++k) acc += a[k] * sU[d][k];
    #pragma unroll
    for (int k = 0; k < 64; ++k) acc += f[k] * sU[d][64 + k];
    out[(size_t)r * 64 + d] = tanhf(acc);
}

// ---------------------------------------------------------------------------
// K2: 16 nodes per 256-thread block, 48.8 KB static LDS (2 blocks/CU).
//  wave0: xw producer (fwd)   wave1: GRU consumer (fwd)
//  wave2: xw producer (bwd)   wave3: GRU consumer (bwd)
// Producers read time-sorted mail rows DIRECTLY from global (L2/L3-hot)
// via sRID. Two serial passes: A) attention scores e via v = glin^T.dst ;
// B) hsum = sum_t alpha[t]*h[t]. Epilogue: hid = glin@hsum + beta@te_k,
// out = agg @ [hid || last_em].
// ---------------------------------------------------------------------------
__global__ __launch_bounds__(256, 2) void reduce16(
    const float* __restrict__ src_hid,   // [Nsrc][64]
    const float* __restrict__ dst_hid,   // [N][64]
    const int*   __restrict__ nbr_idx,   // [N][L]
    const int*   __restrict__ nbr_time,  // [N][L]
    const float* __restrict__ te,        // [L][64]
    const float* __restrict__ te_k,      // [L][64]
    const float* __restrict__ Wi,        // [2][192][64]
    const float* __restrict__ Wh,        // [2][192][64]
    const float* __restrict__ bi,        // [2][192]
    const float* __restrict__ bh,        // [2][192]
    const float* __restrict__ glin,      // [64][128]
    const float* __restrict__ agg,       // [64][128]
    float* __restrict__ out)             // [N][64]
{
    __shared__ __align__(16) char smem[SMEM_SZ];
    uint2* sXWu   = (uint2*)(smem + OFF_XW);
    u16*   sH     = (u16*)(smem + OFF_H);
    float* sEF    = (float*)(smem + OFF_EF);
    float* sEB    = (float*)(smem + OFF_EB);
    float* sAT    = (float*)(smem + OFF_AT);
    u16*   sV     = (u16*)(smem + OFF_V);
    u8*    sORD   = (u8*)(smem + OFF_ORD);
    u8*    sARE   = (u8*)(smem + OFF_ARE);
    int*   sRID   = (int*)(smem + OFF_RID);
    int*   sLASTN = (int*)(smem + OFF_LASTN);

    const int tid  = threadIdx.x;
    const int lane = tid & 63;
    const int wv   = tid >> 6;          // 0..3
    const int l15  = lane & 15;
    const int grp  = lane >> 4;         // 0..3
    const int lk8  = grp * 8;           // bf16 element offset of k-slice
    const int nb   = blockIdx.x * NODES;
    const int dir  = wv >> 1;           // 0=fwd 1=bwd
    const int role = wv & 1;            // 0=producer 1=consumer

    // ---- PH0: load times/ids (scratch in XW region), stable rank, argmax ----
    int* sTM  = (int*)(smem + OFF_XW);
    int* sNID = sTM + NODES * L;
    for (int p = tid; p < NODES * L; p += 256) {
        sTM[p]  = nbr_time[(size_t)nb * L + p];
        sNID[p] = nbr_idx[(size_t)nb * L + p];
    }
    __syncthreads();
    for (int p = tid; p < NODES * L; p += 256) {
        int m = p / L, l = p - m * L;
        int tl = sTM[p], rank = 0;
        for (int mm = 0; mm < L; ++mm) {
            int tm = sTM[m * L + mm];
            rank += (tm < tl) || (tm == tl && mm < l);
        }
        sORD[m * 52 + rank] = (u8)l;
        sARE[m * 52 + l]    = (u8)(L - 1 - rank);
    }
    if (tid < NODES) {
        int best = 0, bt = sTM[tid * L];
        for (int mm = 1; mm < L; ++mm) {
            int tm = sTM[tid * L + mm];
            if (tm > bt) { bt = tm; best = mm; }
        }
        sLASTN[tid] = sNID[tid * L + best];
    }
    __syncthreads();

    // ---- PH1: sorted row-id table + stage dst (bf16) ----
    u16* sDST = (u16*)(smem + OFF_EF);
    for (int p = tid; p < NODES * L; p += 256) {
        int m = p / L, t = p - m * L;
        sRID[m * 52 + t] = sNID[m * L + sORD[m * 52 + t]];
    }
    for (int p = tid; p < NODES * 64; p += 256) {
        int m = p >> 6, d = p & 63;
        sDST[m * 72 + d] = f2bf(dst_hid[(size_t)(nb + m) * 64 + d]);
    }
    __syncthreads();

    // ---- PH2: glin^T stage (XW scratch), v-GEMMs, ted ----
    u16* sGLT = (u16*)(smem + OFF_XW);   // [128][72]
    for (int p = tid; p < 8192; p += 256) {
        int d = p >> 7, j = p & 127;
        sGLT[j * 72 + d] = f2bf(glin[(size_t)d * 128 + j]);
    }
    __syncthreads();
    if (wv < 2) {
        // v[wv][m][j] = sum_d dst[m][d] * glin[d][wv*64 + j]
        bfx8 a0 = *(const bfx8*)(sDST + l15 * 72 + lk8);
        bfx8 a1 = *(const bfx8*)(sDST + l15 * 72 + 32 + lk8);
        #pragma unroll
        for (int nt = 0; nt < 4; ++nt) {
            bfx8 b0 = *(const bfx8*)(sGLT + (wv * 64 + nt * 16 + l15) * 72 + lk8);
            bfx8 b1 = *(const bfx8*)(sGLT + (wv * 64 + nt * 16 + l15) * 72 + 32 + lk8);
            f32x4 acc = {0.f, 0.f, 0.f, 0.f};
            acc = __builtin_amdgcn_mfma_f32_16x16x32_bf16(a0, b0, acc, 0, 0, 0);
            acc = __builtin_amdgcn_mfma_f32_16x16x32_bf16(a1, b1, acc, 0, 0, 0);
            #pragma unroll
            for (int r = 0; r < 4; ++r)
                sV[(wv * 16 + grp * 4 + r) * 72 + nt * 16 + l15] = f2bf(acc[r]);
        }
    } else {
        // ted[m][l] = te[are[m][l]] . dst[m]
        for (int p = tid - 128; p < NODES * L; p += 128) {
            int m = p / L, l = p - m * L;
            const float* tp = te + (size_t)sARE[m * 52 + l] * 64;
            float acc = 0.f;
            #pragma unroll 8
            for (int k = 0; k < 64; ++k) acc += tp[k] * bf2f(sDST[m * 72 + k]);
            sAT[m * 52 + l] = acc;
        }
    }
    __syncthreads();

    // ---- preload weight fragments (Wi for producers, Wh for consumers) ----
    bfx8 wF[12][2];
    float bv[12];
    {
        const float* Wsrc = role ? Wh : Wi;
        const float* bsrc = role ? bh : bi;
        #pragma unroll
        for (int nt = 0; nt < 12; ++nt) {
            const float* wrow = Wsrc + (size_t)(dir * 192 + nt * 16 + l15) * 64;
            wF[nt][0] = pack_bf8(wrow + lk8);
            wF[nt][1] = pack_bf8(wrow + 32 + lk8);
            bv[nt] = bsrc[dir * 192 + nt * 16 + l15];
        }
    }
    float vv[4][4];
    if (role) {
        #pragma unroll
        for (int c = 0; c < 4; ++c)
            #pragma unroll
            for (int r = 0; r < 4; ++r)
                vv[c][r] = bf2f(sV[(dir * 16 + grp * 4 + r) * 72 + c * 16 + l15]);
    }
    float* sE = dir ? sEB : sEF;
    float hp[4][4], S[4][4];

    auto produce = [&](int step, int buf) {
        int tt = dir ? (L - 1 - step) : step;
        const float* mrow = src_hid + (size_t)sRID[l15 * 52 + tt] * 64;
        bfx8 a0 = pack_bf8(mrow + lk8);
        bfx8 a1 = pack_bf8(mrow + 32 + lk8);
        #pragma unroll
        for (int nt = 0; nt < 12; ++nt) {
            f32x4 acc = {0.f, 0.f, 0.f, 0.f};
            acc = __builtin_amdgcn_mfma_f32_16x16x32_bf16(a0, wF[nt][0], acc, 0, 0, 0);
            acc = __builtin_amdgcn_mfma_f32_16x16x32_bf16(a1, wF[nt][1], acc, 0, 0, 0);
            uint2 pk;
            pk.x = (u32)f2bf(acc[0] + bv[nt]) | ((u32)f2bf(acc[1] + bv[nt]) << 16);
            pk.y = (u32)f2bf(acc[2] + bv[nt]) | ((u32)f2bf(acc[3] + bv[nt]) << 16);
            sXWu[(((dir * 2 + buf) * 12 + nt) * 16 + l15) * 4 + grp] = pk;
        }
    };

    auto consume = [&](int s, int buf, int pass) {
        uint2 xwu[12];
        #pragma unroll
        for (int nt = 0; nt < 12; ++nt)
            xwu[nt] = sXWu[(((dir * 2 + buf) * 12 + nt) * 16 + l15) * 4 + grp];
        const u16* hrow = sH + (dir * 16 + l15) * 72;
        bfx8 a0 = *(const bfx8*)(hrow + lk8);
        bfx8 a1 = *(const bfx8*)(hrow + 32 + lk8);
        f32x4 accd[12];
        #pragma unroll
        for (int nt = 0; nt < 12; ++nt) {
            f32x4 z = {0.f, 0.f, 0.f, 0.f};
            z = __builtin_amdgcn_mfma_f32_16x16x32_bf16(a0, wF[nt][0], z, 0, 0, 0);
            z = __builtin_amdgcn_mfma_f32_16x16x32_bf16(a1, wF[nt][1], z, 0, 0, 0);
            accd[nt] = z;
        }
        int t = dir ? (L - 1 - s) : s;
        float al[4];
        if (pass == 1) {
            #pragma unroll
            for (int r = 0; r < 4; ++r) al[r] = sAT[(grp * 4 + r) * 52 + t];
        }
        float pe[4] = {0.f, 0.f, 0.f, 0.f};
        #pragma unroll
        for (int c = 0; c < 4; ++c) {
            #pragma unroll
            for (int r = 0; r < 4; ++r) {
                float ghr = accd[c][r]     + bv[c];
                float ghz = accd[4 + c][r] + bv[4 + c];
                float ghn = accd[8 + c][r] + bv[8 + c];
                float xwr = xget(xwu[c], r);
                float xwz = xget(xwu[4 + c], r);
                float xwn = xget(xwu[8 + c], r);
                float rr = fsig(xwr + ghr);
                float zz = fsig(xwz + ghz);
                float nn = ftanh(xwn + rr * ghn);
                float h  = (1.f - zz) * nn + zz * hp[c][r];
                hp[c][r] = h;
                sH[(dir * 16 + grp * 4 + r) * 72 + c * 16 + l15] = f2bf(h);
                if (pass == 0) pe[r] += h * vv[c][r];
                else           S[c][r] += al[r] * h;
            }
        }
        if (pass == 0) {
            #pragma unroll
            for (int r = 0; r < 4; ++r) {
                #pragma unroll
                for (int msk = 1; msk < 16; msk <<= 1)
                    pe[r] += __shfl_xor(pe[r], msk, 64);
            }
            if (l15 == 0) {
                #pragma unroll
                for (int r = 0; r < 4; ++r)
                    sE[(grp * 4 + r) * 52 + t] = pe[r];
            }
        }
    };

    // ---- PH3/PH5: the two serial passes ----
    for (int pass = 0; pass < 2; ++pass) {
        if (role == 0) {
            produce(0, 0);
        } else {
            #pragma unroll
            for (int c = 0; c < 4; ++c)
                #pragma unroll
                for (int r = 0; r < 4; ++r) {
                    hp[c][r] = 0.f; S[c][r] = (pass == 0) ? S[c][r] : 0.f;
                    sH[(dir * 16 + grp * 4 + r) * 72 + c * 16 + l15] = 0;
                }
        }
        __syncthreads();
        for (int s = 0; s < L; ++s) {
            if (role == 0) {
                if (s + 1 < L) produce(s + 1, (s + 1) & 1);
            } else {
                consume(s, s & 1, pass);
            }
            __syncthreads();
        }
        if (pass == 0) {
            // ---- PH4: softmax over t per node; alpha -> sAT ----
            if (tid < NODES) {
                int m = tid;
                float mx = -1e30f;
                for (int t = 0; t < L; ++t) {
                    float v = (sEF[m * 52 + t] + sEB[m * 52 + t] + sAT[m * 52 + t]) * 0.125f;
                    sEF[m * 52 + t] = v;
                    mx = fmaxf(mx, v);
                }
                float sum = 0.f;
                for (int t = 0; t < L; ++t) {
                    float ex = __expf(sEF[m * 52 + t] - mx);
                    sEF[m * 52 + t] = ex;
                    sum += ex;
                }
                float rs = __builtin_amdgcn_rcpf(sum);
                for (int t = 0; t < L; ++t) sAT[m * 52 + t] = sEF[m * 52 + t] * rs;
            }
            __syncthreads();
        }
    }

    // ---- PH6: epilogue (XW region is dead -> sHS / sA9 / sTKT) ----
    u16* sHS   = (u16*)(smem + OFF_XW);              // [16][136] bf16  hsum f||b
    u16* sA9   = sHS + 16 * 136;                     // [16][136] bf16  hid || last_em
    u16* sTKT  = sA9 + 16 * 136;                     // [64][72]  bf16  te_k^T (zero-padded)
    u16* sBETA = (u16*)(smem + OFF_EB);              // [16][72]  bf16

    if (role == 1) {
        #pragma unroll
        for (int c = 0; c < 4; ++c)
            #pragma unroll
            for (int r = 0; r < 4; ++r)
                sHS[(grp * 4 + r) * 136 + dir * 64 + c * 16 + l15] = f2bf(S[c][r]);
    }
    if (tid < NODES) {
        for (int t = 0; t < L; ++t)
            sBETA[tid * 72 + sARE[tid * 52 + t]] = f2bf(sAT[tid * 52 + t]);
        for (int j = L; j < 64; ++j) sBETA[tid * 72 + j] = 0;
    }
    for (int p = tid; p < 4096; p += 256) {
        int j = p >> 6, d = p & 63;
        sTKT[d * 72 + j] = (j < L) ? f2bf(te_k[(size_t)j * 64 + d]) : (u16)0;
    }
    for (int p = tid; p < NODES * 64; p += 256) {
        int m = p >> 6, d = p & 63;
        sA9[m * 136 + 64 + d] = f2bf(src_hid[(size_t)sLASTN[m] * 64 + d]);
    }
    __syncthreads();

    // hid[m][d] = glin[d][:].hsum[m] + te_k^T[d][:].beta[m]  (wave wv = N-tile)
    {
        int nt = wv;
        bfx8 aH[4], aB[2];
        #pragma unroll
        for (int kt = 0; kt < 4; ++kt)
            aH[kt] = *(const bfx8*)(sHS + l15 * 136 + kt * 32 + lk8);
        #pragma unroll
        for (int kt = 0; kt < 2; ++kt)
            aB[kt] = *(const bfx8*)(sBETA + l15 * 72 + kt * 32 + lk8);
        f32x4 acc = {0.f, 0.f, 0.f, 0.f};
        #pragma unroll
        for (int kt = 0; kt < 4; ++kt) {
            bfx8 b = pack_bf8(glin + (size_t)(nt * 16 + l15) * 128 + kt * 32 + lk8);
            acc = __builtin_amdgcn_mfma_f32_16x16x32_bf16(aH[kt], b, acc, 0, 0, 0);
        }
        #pragma unroll
        for (int kt = 0; kt < 2; ++kt) {
            bfx8 b = *(const bfx8*)(sTKT + (nt * 16 + l15) * 72 + kt * 32 + lk8);
            acc = __builtin_amdgcn_mfma_f32_16x16x32_bf16(aB[kt], b, acc, 0, 0, 0);
        }
        #pragma unroll
        for (int r = 0; r < 4; ++r)
            sA9[(grp * 4 + r) * 136 + nt * 16 + l15] = f2bf(acc[r]);
    }
    __syncthreads();

    // out[m][d] = agg[d][:64].hid[m] + agg[d][64:].last_em[m]
    {
        int nt = wv;
        bfx8 aA[4];
        #pragma unroll
        for (int kt = 0; kt < 4; ++kt)
            aA[kt] = *(const bfx8*)(sA9 + l15 * 136 + kt * 32 + lk8);
        f32x4 acc = {0.f, 0.f, 0.f, 0.f};
        #pragma unroll
        for (int kt = 0; kt < 4; ++kt) {
            bfx8 b = pack_bf8(agg + (size_t)(nt * 16 + l15) * 128 + kt * 32 + lk8);
            acc = __builtin_amdgcn_mfma_f32_16x16x32_bf16(aA[kt], b, acc, 0, 0, 0);
        }
        #pragma unroll
        for (int r = 0; r < 4; ++r)
            out[(size_t)(nb + grp * 4 + r) * 64 + nt * 16 + l15] = acc[r];
    }
}

// ---------------------------------------------------------------------------
extern "C" void kernel_launch(void* const* d_in, const int* in_sizes, int n_in,
                              void* d_out, int out_size, void* d_ws, size_t ws_size,
                              hipStream_t stream)
{
    const float* user_feat     = (const float*)d_in[0];
    const float* item_feat     = (const float*)d_in[1];
    const int*   item_nbr_idx  = (const int*)d_in[2];
    const int*   item_nbr_time = (const int*)d_in[3];
    const int*   user_nbr_idx  = (const int*)d_in[4];
    const int*   user_nbr_time = (const int*)d_in[5];
    const float* W_user        = (const float*)d_in[6];
    const float* W_item        = (const float*)d_in[7];
    const float* u_te          = (const float*)d_in[8];
    const float* u_te_k        = (const float*)d_in[9];
    const float* i_te          = (const float*)d_in[10];
    const float* i_te_k        = (const float*)d_in[11];
    const float* gru_u_Wi      = (const float*)d_in[12];
    const float* gru_u_Wh      = (const float*)d_in[13];
    const float* gru_u_bi      = (const float*)d_in[14];
    const float* gru_u_bh      = (const float*)d_in[15];
    const float* gru_i_Wi      = (const float*)d_in[16];
    const float* gru_i_Wh      = (const float*)d_in[17];
    const float* gru_i_bi      = (const float*)d_in[18];
    const float* gru_i_bh      = (const float*)d_in[19];
    const float* gru_lin_u     = (const float*)d_in[20];
    const float* gru_lin_i     = (const float*)d_in[21];
    const float* agg_u         = (const float*)d_in[22];
    const float* agg_i         = (const float*)d_in[23];
    const float* upd_u         = (const float*)d_in[24];
    const float* upd_i         = (const float*)d_in[25];

    float* ws       = (float*)d_ws;
    float* user_hid = ws;
    float* item_hid = user_hid + NU * 64;
    float* item_agg = item_hid + NI * 64;
    float* user_agg = item_agg + NI * 64;

    hid_kernel<<<NU / 4, 256, 0, stream>>>(user_feat, W_user, user_hid, NU);
    hid_kernel<<<NI / 4, 256, 0, stream>>>(item_feat, W_item, item_hid, NI);

    // 'by': user -> item, per item node
    reduce16<<<NI / NODES, 256, 0, stream>>>(user_hid, item_hid,
        item_nbr_idx, item_nbr_time, i_te, i_te_k,
        gru_i_Wi, gru_i_Wh, gru_i_bi, gru_i_bh, gru_lin_i, agg_i, item_agg);

    // 'pby': item -> user, per user node
    reduce16<<<NU / NODES, 256, 0, stream>>>(item_hid, user_hid,
        user_nbr_idx, user_nbr_time, u_te, u_te_k,
        gru_u_Wi, gru_u_Wh, gru_u_bi, gru_u_bh, gru_lin_u, agg_u, user_agg);

    float* out = (float*)d_out;
    upd_kernel<<<NU / 4, 256, 0, stream>>>(user_agg, user_feat, upd_u, out, NU);
    upd_kernel<<<NI / 4, 256, 0, stream>>>(item_agg, item_feat, upd_i, out + NU * 64, NI);
}